// Round 1
// baseline (142.794 us; speedup 1.0000x reference)
//
#include <hip/hip_runtime.h>
#include <hip/hip_bf16.h>

#define TWO_N 8192
#define DIMS  256

typedef __bf16 bf16x8 __attribute__((ext_vector_type(8)));
typedef float  f32x4  __attribute__((ext_vector_type(4)));

// ---------------------------------------------------------------------------
// Kernel 1: normalize rows of reps = cat([zjs, zis]) and cast to bf16.
// One wave per row (4 rows / 256-thread block). 2048 blocks.
// ---------------------------------------------------------------------------
__global__ __launch_bounds__(256) void nrm_kernel(const float* __restrict__ zis,
                                                  const float* __restrict__ zjs,
                                                  unsigned short* __restrict__ out)
{
    const int row  = blockIdx.x * 4 + (threadIdx.x >> 6);
    const int lane = threadIdx.x & 63;
    const float* src = (row < TWO_N / 2) ? (zjs + (size_t)row * DIMS)
                                         : (zis + (size_t)(row - TWO_N / 2) * DIMS);
    const float4 v = reinterpret_cast<const float4*>(src)[lane];
    float ss = v.x * v.x + v.y * v.y + v.z * v.z + v.w * v.w;
#pragma unroll
    for (int m = 1; m < 64; m <<= 1) ss += __shfl_xor(ss, m, 64);
    const float inv = rsqrtf(ss);   // norms ~16 for N(0,1) rows; eps path never active

    __hip_bfloat16 b0 = __float2bfloat16(v.x * inv);
    __hip_bfloat16 b1 = __float2bfloat16(v.y * inv);
    __hip_bfloat16 b2 = __float2bfloat16(v.z * inv);
    __hip_bfloat16 b3 = __float2bfloat16(v.w * inv);
    ushort4 o;
    o.x = *reinterpret_cast<unsigned short*>(&b0);
    o.y = *reinterpret_cast<unsigned short*>(&b1);
    o.z = *reinterpret_cast<unsigned short*>(&b2);
    o.w = *reinterpret_cast<unsigned short*>(&b3);
    reinterpret_cast<ushort4*>(out + (size_t)row * DIMS)[lane] = o;
}

// ---------------------------------------------------------------------------
// Kernel 2: fused sim = N @ N^T (bf16 MFMA), exp(sim/TEMP) row-partial-sums,
// diagonal masking, positive-pair extraction.
//
// Grid: 1024 blocks x 256 threads (4 waves).
//   blockIdx & 31  -> row group (256 rows), blockIdx >> 5 -> col split (256 cols)
//   wave w handles rows [rg*256 + w*64, +64), all 256 cols of the split.
// Per wave: B-fragments for its 64 rows hoisted once into 128 VGPRs; 16 col
// tiles of 16; per tile 8 A-frag loads (L2-resident) + 32 MFMA + 16 exp2/lane.
// MFMA D layout (16x16x32): col = lane&15 (-> our row r), row = quad*4+reg
// (-> our col c). A-frag: A[m=lane&15][k=quad*8+j]; B-frag: B[k][n=lane&15].
// ---------------------------------------------------------------------------
__global__ __launch_bounds__(256, 2) void ntx_kernel(const __bf16* __restrict__ nrm,
                                                     float* __restrict__ rowsum,
                                                     float* __restrict__ pos_out)
{
    const int lane = threadIdx.x & 63;
    const int wave = threadIdx.x >> 6;
    const int l15  = lane & 15;
    const int quad = lane >> 4;

    const int rg     = blockIdx.x & 31;
    const int cs     = blockIdx.x >> 5;
    const int wr0    = rg * 256 + wave * 64;    // this wave's 64 rows
    const int c_base = cs * 256;                // this wave's 256 cols

    // Hoist B (row) fragments: rows wr0 + t*16 + l15, k = kk*32 + quad*8 + j
    bf16x8 bfrag[4][8];
#pragma unroll
    for (int t = 0; t < 4; ++t) {
        const __bf16* rp = nrm + (size_t)(wr0 + t * 16 + l15) * DIMS + quad * 8;
#pragma unroll
        for (int kk = 0; kk < 8; ++kk)
            bfrag[t][kk] = *reinterpret_cast<const bf16x8*>(rp + kk * 32);
    }

    float sum_exp[4] = {0.f, 0.f, 0.f, 0.f};
    float pos_acc = 0.f;
    const int p0 = wr0 ^ (TWO_N / 2);           // partner-row block of this wave
    const float SC = 2.0f * 1.4426950408889634f;  // (1/TEMP) * log2(e)

    for (int it = 0; it < 16; ++it) {
        const int c0 = c_base + it * 16;
        const __bf16* cp = nrm + (size_t)(c0 + l15) * DIMS + quad * 8;
        bf16x8 afrag[8];
#pragma unroll
        for (int kk = 0; kk < 8; ++kk)
            afrag[kk] = *reinterpret_cast<const bf16x8*>(cp + kk * 32);

        f32x4 acc[4] = {{0.f, 0.f, 0.f, 0.f}, {0.f, 0.f, 0.f, 0.f},
                        {0.f, 0.f, 0.f, 0.f}, {0.f, 0.f, 0.f, 0.f}};
#pragma unroll
        for (int kk = 0; kk < 8; ++kk) {
#pragma unroll
            for (int t = 0; t < 4; ++t)
                acc[t] = __builtin_amdgcn_mfma_f32_16x16x32_bf16(
                    afrag[kk], bfrag[t][kk], acc[t], 0, 0, 0);
        }
        // D[m][n]: value = sim[row = wr0+t*16+l15][col = c0+quad*4+j]
        const bool special = (c0 < wr0 + 64 && c0 + 16 > wr0) ||
                             (c0 < p0 + 64 && c0 + 16 > p0);
        if (!special) {
#pragma unroll
            for (int t = 0; t < 4; ++t)
#pragma unroll
                for (int j = 0; j < 4; ++j)
                    sum_exp[t] += exp2f(acc[t][j] * SC);
        } else {
#pragma unroll
            for (int t = 0; t < 4; ++t) {
                const int r = wr0 + t * 16 + l15;
#pragma unroll
                for (int j = 0; j < 4; ++j) {
                    const int c = c0 + quad * 4 + j;
                    const float e = exp2f(acc[t][j] * SC);
                    sum_exp[t] += (c == r) ? 0.f : e;            // mask self-diag
                    if (c == (r ^ (TWO_N / 2))) pos_acc += acc[t][j];  // positive pair
                }
            }
        }
    }

    // Reduce sum_exp across the 4 quads (cols) -> per-row partial, one atomic/row.
#pragma unroll
    for (int t = 0; t < 4; ++t) {
        float s = sum_exp[t];
        s += __shfl_xor(s, 16, 64);
        s += __shfl_xor(s, 32, 64);
        if (lane < 16) atomicAdd(&rowsum[wr0 + t * 16 + lane], s);
    }

    // Positive-pair partial: only waves whose col split contains the partner block.
    if (c_base < p0 + 64 && c_base + 256 > p0) {
#pragma unroll
        for (int m = 1; m < 64; m <<= 1) pos_acc += __shfl_xor(pos_acc, m, 64);
        if (lane == 0) atomicAdd(pos_out, pos_acc);
    }
}

// ---------------------------------------------------------------------------
// Kernel 3: loss = (sum_i log(rowsum[i]) - 2 * pos_total) / 2N
// ---------------------------------------------------------------------------
__global__ __launch_bounds__(1024) void fin_kernel(const float* __restrict__ rowsum,
                                                   const float* __restrict__ pos_total,
                                                   float* __restrict__ out)
{
    __shared__ float red[16];
    const int tid = threadIdx.x;
    float acc = 0.f;
    for (int i = tid; i < TWO_N; i += 1024)
        acc += logf(rowsum[i]);
#pragma unroll
    for (int m = 1; m < 64; m <<= 1) acc += __shfl_xor(acc, m, 64);
    if ((tid & 63) == 0) red[tid >> 6] = acc;
    __syncthreads();
    if (tid == 0) {
        float tot = 0.f;
#pragma unroll
        for (int w = 0; w < 16; ++w) tot += red[w];
        out[0] = (tot - 2.0f * pos_total[0]) / (float)TWO_N;
    }
}

// ---------------------------------------------------------------------------
extern "C" void kernel_launch(void* const* d_in, const int* in_sizes, int n_in,
                              void* d_out, int out_size, void* d_ws, size_t ws_size,
                              hipStream_t stream)
{
    const float* zis = (const float*)d_in[0];
    const float* zjs = (const float*)d_in[1];

    // ws layout: [0, 4MB) bf16 normalized matrix; [4MB, +32KB) rowsum; then pos.
    unsigned short* nrm_u16 = (unsigned short*)d_ws;
    float* rowsum    = (float*)((char*)d_ws + (size_t)TWO_N * DIMS * sizeof(unsigned short));
    float* pos_total = rowsum + TWO_N;

    hipMemsetAsync(rowsum, 0, (TWO_N + 1) * sizeof(float), stream);
    nrm_kernel<<<TWO_N / 4, 256, 0, stream>>>(zis, zjs, nrm_u16);
    ntx_kernel<<<1024, 256, 0, stream>>>((const __bf16*)d_ws, rowsum, pos_total);
    fin_kernel<<<1, 1024, 0, stream>>>(rowsum, pos_total, (float*)d_out);
}

// Round 2
// 96.040 us; speedup vs baseline: 1.4868x; 1.4868x over previous
//
#include <hip/hip_runtime.h>
#include <hip/hip_bf16.h>

#define TWO_N  8192
#define N_HALF 4096
#define DIMS   256

typedef __bf16 bf16x8 __attribute__((ext_vector_type(8)));
typedef float  f32x4  __attribute__((ext_vector_type(4)));
typedef unsigned short ushort8v __attribute__((ext_vector_type(8)));

// raw v_exp_f32 (args here are bounded |x| <= ~3, no denormal/range handling needed)
__device__ __forceinline__ float fast_exp2(float x) {
#if __has_builtin(__builtin_amdgcn_exp2f)
    return __builtin_amdgcn_exp2f(x);
#else
    float r; asm("v_exp_f32 %0, %1" : "=v"(r) : "v"(x)); return r;
#endif
}

// ---------------------------------------------------------------------------
// Kernel 1: normalize rows of reps = cat([zjs, zis]), pre-scale by
// sqrt(2*log2(e)) so MFMA dot = (1/TEMP)*log2(e)*sim, and store in MFMA
// fragment-swizzled order: chunk = ((row/16)*8 + kk)*64 + quad*16 + (row%16),
// each chunk = 8 bf16 = elements k in [quad*8 + kk*32, +8) of that row.
// One 32-lane half-wave per row (8 rows / 256-thread block).
// ---------------------------------------------------------------------------
__global__ __launch_bounds__(256) void nrm_kernel(const float* __restrict__ zis,
                                                  const float* __restrict__ zjs,
                                                  unsigned short* __restrict__ swz)
{
    const int tid = threadIdx.x;
    const int l32 = tid & 31;
    const int row = blockIdx.x * 8 + (tid >> 5);
    const int k0  = l32 * 8;

    const float* src = (row < N_HALF) ? (zjs + (size_t)row * DIMS)
                                      : (zis + (size_t)(row - N_HALF) * DIMS);
    const float4 v0 = reinterpret_cast<const float4*>(src + k0)[0];
    const float4 v1 = reinterpret_cast<const float4*>(src + k0 + 4)[0];
    float ss = v0.x * v0.x + v0.y * v0.y + v0.z * v0.z + v0.w * v0.w
             + v1.x * v1.x + v1.y * v1.y + v1.z * v1.z + v1.w * v1.w;
#pragma unroll
    for (int m = 1; m < 32; m <<= 1) ss += __shfl_xor(ss, m, 64);
    // norms ~16 for N(0,1) rows; cosine eps path can never trigger
    const float inv = rsqrtf(ss) * 1.69864360045f;  // * sqrt(2*log2(e))

    const float vals[8] = {v0.x, v0.y, v0.z, v0.w, v1.x, v1.y, v1.z, v1.w};
    ushort8v o;
#pragma unroll
    for (int j = 0; j < 8; ++j) {
        __hip_bfloat16 b = __float2bfloat16(vals[j] * inv);
        o[j] = *reinterpret_cast<unsigned short*>(&b);
    }
    // kk = k0>>5 = l32>>2, quad = l32&3
    const int chunk = ((row >> 4) * 8 + (l32 >> 2)) * 64 + (l32 & 3) * 16 + (row & 15);
    *reinterpret_cast<ushort8v*>(swz + (size_t)chunk * 8) = o;
}

// ---------------------------------------------------------------------------
// Kernel 2: fused scaled-Gram (bf16 MFMA) + exp2 row partial sums + diag mask
// + positive extraction. Grid 1024x256 (4 waves): blockIdx&31 -> row group
// (256 rows), blockIdx>>5 -> col split (256 cols). Wave w: rows wr0..wr0+63.
// All fragment loads are fully coalesced 1KB wave loads from the swizzled
// buffer; A tiles are register double-buffered.
// ---------------------------------------------------------------------------
__global__ __launch_bounds__(256, 2) void ntx_kernel(const __bf16* __restrict__ swz,
                                                     float* __restrict__ rowsum_part,
                                                     float* __restrict__ pos_part)
{
    const int lane = threadIdx.x & 63;
    const int wave = threadIdx.x >> 6;
    const int l15  = lane & 15;
    const int quad = lane >> 4;

    const int rg     = blockIdx.x & 31;
    const int cs     = blockIdx.x >> 5;
    const int wr0    = rg * 256 + wave * 64;
    const int c_base = cs * 256;
    const int p0     = wr0 ^ N_HALF;   // partner-row block (positives)

    // Hoist B (row) fragments: 4 groups of 16 rows, 8 K-chunks each.
    bf16x8 bfrag[4][8];
#pragma unroll
    for (int t = 0; t < 4; ++t) {
        const __bf16* bp = swz + (size_t)((wr0 >> 4) + t) * 4096 + lane * 8;
#pragma unroll
        for (int kk = 0; kk < 8; ++kk)
            bfrag[t][kk] = *reinterpret_cast<const bf16x8*>(bp + kk * 512);
    }

    const __bf16* abase = swz + (size_t)(cs * 16) * 4096 + lane * 8;

    float sum_exp[4] = {0.f, 0.f, 0.f, 0.f};
    float pos_acc = 0.f;

    bf16x8 a0[8], a1[8];
#pragma unroll
    for (int kk = 0; kk < 8; ++kk)
        a0[kk] = *reinterpret_cast<const bf16x8*>(abase + kk * 512);

    auto compute = [&](const bf16x8* af, int it) {
        const int c0 = c_base + it * 16;
        f32x4 acc[4] = {{0.f, 0.f, 0.f, 0.f}, {0.f, 0.f, 0.f, 0.f},
                        {0.f, 0.f, 0.f, 0.f}, {0.f, 0.f, 0.f, 0.f}};
#pragma unroll
        for (int kk = 0; kk < 8; ++kk) {
#pragma unroll
            for (int t = 0; t < 4; ++t)
                acc[t] = __builtin_amdgcn_mfma_f32_16x16x32_bf16(
                    af[kk], bfrag[t][kk], acc[t], 0, 0, 0);
        }
        // acc = (1/TEMP)*log2(e)*sim ; D[m=row l15][n-> col quad*4+j]
        const bool special = (c0 < wr0 + 64 && c0 + 16 > wr0) ||
                             (c0 < p0 + 64 && c0 + 16 > p0);
        if (!special) {
#pragma unroll
            for (int t = 0; t < 4; ++t)
#pragma unroll
                for (int j = 0; j < 4; ++j)
                    sum_exp[t] += fast_exp2(acc[t][j]);
        } else {
#pragma unroll
            for (int t = 0; t < 4; ++t) {
                const int r = wr0 + t * 16 + l15;
#pragma unroll
                for (int j = 0; j < 4; ++j) {
                    const int c = c0 + quad * 4 + j;
                    const float e = fast_exp2(acc[t][j]);
                    sum_exp[t] += (c == r) ? 0.f : e;               // self-diag mask
                    if (c == (r ^ N_HALF)) pos_acc += acc[t][j];    // positive (scaled dot)
                }
            }
        }
    };

    for (int it = 0; it < 16; it += 2) {
#pragma unroll
        for (int kk = 0; kk < 8; ++kk)
            a1[kk] = *reinterpret_cast<const bf16x8*>(abase + (size_t)(it + 1) * 4096 + kk * 512);
        compute(a0, it);
        if (it + 2 < 16) {
#pragma unroll
            for (int kk = 0; kk < 8; ++kk)
                a0[kk] = *reinterpret_cast<const bf16x8*>(abase + (size_t)(it + 2) * 4096 + kk * 512);
        }
        compute(a1, it + 1);
    }

    // Per-row partial: reduce over the 4 quads (col groups), one store per row.
#pragma unroll
    for (int t = 0; t < 4; ++t) {
        float s = sum_exp[t];
        s += __shfl_xor(s, 16, 64);
        s += __shfl_xor(s, 32, 64);
        if (lane < 16)
            rowsum_part[(size_t)cs * TWO_N + wr0 + t * 16 + lane] = s;
    }

    // Positive partial: every wave writes its slot (0 if no partner overlap).
#pragma unroll
    for (int m = 1; m < 64; m <<= 1) pos_acc += __shfl_xor(pos_acc, m, 64);
    if (lane == 0) pos_part[blockIdx.x * 4 + wave] = pos_acc;
}

// ---------------------------------------------------------------------------
// Kernel 3: per-row ln(sum of 32 partials), minus ln2 * positive partials,
// block-reduced. 8 blocks x 1024 threads, coalesced reads.
// ---------------------------------------------------------------------------
__global__ __launch_bounds__(1024) void fin1_kernel(const float* __restrict__ rowsum_part,
                                                    const float* __restrict__ pos_part,
                                                    float* __restrict__ block_part)
{
    __shared__ float red[16];
    const int t = threadIdx.x;
    const int r = blockIdx.x * 1024 + t;
    float acc = 0.f;
#pragma unroll
    for (int cs = 0; cs < 32; ++cs)
        acc += rowsum_part[(size_t)cs * TWO_N + r];
    float v = logf(acc);
    if (t < 512)
        v -= 0.69314718055994531f * pos_part[blockIdx.x * 512 + t];
#pragma unroll
    for (int m = 1; m < 64; m <<= 1) v += __shfl_xor(v, m, 64);
    if ((t & 63) == 0) red[t >> 6] = v;
    __syncthreads();
    if (t == 0) {
        float s = 0.f;
#pragma unroll
        for (int w = 0; w < 16; ++w) s += red[w];
        block_part[blockIdx.x] = s;
    }
}

// ---------------------------------------------------------------------------
// Kernel 4: final scalar.
// ---------------------------------------------------------------------------
__global__ void fin2_kernel(const float* __restrict__ block_part, float* __restrict__ out)
{
    if (threadIdx.x == 0) {
        float s = 0.f;
#pragma unroll
        for (int i = 0; i < 8; ++i) s += block_part[i];
        out[0] = s / (float)TWO_N;
    }
}

// ---------------------------------------------------------------------------
extern "C" void kernel_launch(void* const* d_in, const int* in_sizes, int n_in,
                              void* d_out, int out_size, void* d_ws, size_t ws_size,
                              hipStream_t stream)
{
    const float* zis = (const float*)d_in[0];
    const float* zjs = (const float*)d_in[1];

    // ws: [0,4MB) swizzled bf16; [4MB,+1MB) rowsum partials [32][8192];
    //     then pos partials [4096]; then block partials [8].
    unsigned short* swz = (unsigned short*)d_ws;
    float* rowsum_part  = (float*)((char*)d_ws + (size_t)TWO_N * DIMS * sizeof(unsigned short));
    float* pos_part     = rowsum_part + (size_t)32 * TWO_N;
    float* block_part   = pos_part + 4096;

    nrm_kernel<<<TWO_N / 8, 256, 0, stream>>>(zis, zjs, swz);
    ntx_kernel<<<1024, 256, 0, stream>>>((const __bf16*)swz, rowsum_part, pos_part);
    fin1_kernel<<<8, 1024, 0, stream>>>(rowsum_part, pos_part, block_part);
    fin2_kernel<<<1, 64, 0, stream>>>(block_part, (float*)d_out);
}